// Round 5
// baseline (142.316 us; speedup 1.0000x reference)
//
#include <hip/hip_runtime.h>
#include <hip/hip_bf16.h>

// NT-Xent (SimCLR) fused loss, MI355X gfx950. Round 5: LDS-free GEMM.
// K=256 is tiny and zn (4MB) is L2-resident, so each wave loads its MFMA
// fragments DIRECTLY from global (16-row x 64B coalesced segments, L1-hit
// on the 2x wave duplication) and never touches LDS or __syncthreads.
// This removes the 8 per-block vmcnt(0)+barrier drains that held round 3's
// tile kernel at MfmaUtil 15%. 128x128 tile, upper-triangle enumeration,
// row+col sum epilogue, plain atomics, separate finalize (round-3 semantics).
//
// ws layout: [S: N floats][pos: N floats][zn: N*D bf16]

#define N_TOT 8192
#define BATCH 4096
#define DIM   256
#define NT_TILES 64                  // 8192 / 128

typedef short bf16x8 __attribute__((ext_vector_type(8)));
typedef float f32x4  __attribute__((ext_vector_type(4)));

__device__ __forceinline__ unsigned short f32_to_bf16(float f) {
  unsigned int u = __float_as_uint(f);
  u += 0x7fff + ((u >> 16) & 1);   // RNE
  return (unsigned short)(u >> 16);
}

// One wave per row: 64 lanes x float4 = 256 elements. Also zeros S.
__global__ __launch_bounds__(256) void normalize_kernel(
    const float* __restrict__ z, unsigned short* __restrict__ zn,
    float* __restrict__ S) {
  const int wave = threadIdx.x >> 6;
  const int lane = threadIdx.x & 63;
  const int row  = blockIdx.x * 4 + wave;
  float4 v = ((const float4*)(z + (size_t)row * DIM))[lane];
  float ss = v.x * v.x + v.y * v.y + v.z * v.z + v.w * v.w;
#pragma unroll
  for (int m = 1; m <= 32; m <<= 1) ss += __shfl_xor(ss, m);
  float inv = 1.0f / sqrtf(ss);
  ushort4 o;
  o.x = f32_to_bf16(v.x * inv);
  o.y = f32_to_bf16(v.y * inv);
  o.z = f32_to_bf16(v.z * inv);
  o.w = f32_to_bf16(v.w * inv);
  ((ushort4*)(zn + (size_t)row * DIM))[lane] = o;
  if (threadIdx.x < 4) S[blockIdx.x * 4 + threadIdx.x] = 0.0f;
}

// Upper-triangle 128x128 tiles of sim = zn*zn^T*10, fused exp + row/col sums.
// Grid (33, 64): j = blockIdx.x in [0,32], rb_raw = blockIdx.y.
// cb_raw = (rb_raw + j) % 64; j==32 only for rb_raw < 32.
// 4 waves in 2x2, each owns a 64x64 quadrant = 4x4 fragments of 16x16x32.
// NO LDS, NO BARRIERS: fragments load straight from global (L1/L2-resident).
__global__ __launch_bounds__(256, 4) void simclr_tile_kernel(
    const unsigned short* __restrict__ zn, float* __restrict__ S,
    float* __restrict__ pos) {
  const int j = blockIdx.x, rb_raw = blockIdx.y;
  if (j == 32 && rb_raw >= 32) return;

  const int tid = threadIdx.x;
  const int wave = tid >> 6, lane = tid & 63;
  const int wm = wave >> 1, wn = wave & 1;      // wave quadrant (2x2)
  const int c = lane & 15, quad = lane >> 4;    // MFMA lane coords

  int cb_raw = rb_raw + j;
  if (cb_raw >= NT_TILES) cb_raw -= NT_TILES;
  const int rb = (cb_raw < rb_raw) ? cb_raw : rb_raw;
  const int cb = (cb_raw < rb_raw) ? rb_raw : cb_raw;
  const bool isdiag = (j == 0);

  f32x4 acc[4][4];
#pragma unroll
  for (int i = 0; i < 4; ++i)
#pragma unroll
    for (int jj = 0; jj < 4; ++jj) acc[i][jj] = (f32x4){0.f, 0.f, 0.f, 0.f};

  // A-fragment for 16x16x32: lane(c,quad) holds A[row=c][k=quad*8 .. +8]
  // -> 8 contiguous bf16 = one 16B global load; 16 rows x 64B coalesced.
  const unsigned short* baseA =
      zn + (size_t)(rb * 128 + wm * 64 + c) * DIM + quad * 8;
  const unsigned short* baseB =
      zn + (size_t)(cb * 128 + wn * 64 + c) * DIM + quad * 8;

#pragma unroll
  for (int kc = 0; kc < DIM / 32; ++kc) {       // 8 K-chunks of 32
    bf16x8 af[4], bfr[4];
#pragma unroll
    for (int f = 0; f < 4; ++f) {
      af[f]  = *(const bf16x8*)(baseA + (size_t)f * 16 * DIM + kc * 32);
      bfr[f] = *(const bf16x8*)(baseB + (size_t)f * 16 * DIM + kc * 32);
    }
#pragma unroll
    for (int fm = 0; fm < 4; ++fm)
#pragma unroll
      for (int fn = 0; fn < 4; ++fn)
        acc[fm][fn] = __builtin_amdgcn_mfma_f32_16x16x32_bf16(
            af[fm], bfr[fn], acc[fm][fn], 0, 0, 0);
  }

  // Epilogue. C/D layout: row = quad*4 + reg, col = lane&15 per 16x16 frag.
  float cs[4] = {0.f, 0.f, 0.f, 0.f};           // per-lane column partials
#pragma unroll
  for (int fm = 0; fm < 4; ++fm) {
#pragma unroll
    for (int r = 0; r < 4; ++r) {
      const int grow = rb * 128 + wm * 64 + fm * 16 + quad * 4 + r;
      float s = 0.f;
#pragma unroll
      for (int fn = 0; fn < 4; ++fn) {
        const int gcol = cb * 128 + wn * 64 + fn * 16 + c;
        const float logit = acc[fm][fn][r] * 10.0f;
        float e = __expf(logit);
        if (isdiag && gcol == grow) e = 0.f;    // exclude self-similarity
        if (!isdiag && gcol == grow + BATCH) {  // partner pair (i, i+B):
          pos[grow] = logit;                    // unique writer per element
          pos[gcol] = logit;                    // sim symmetric -> same value
        }
        s += e;
        cs[fn] += e;
      }
      s += __shfl_xor(s, 1);
      s += __shfl_xor(s, 2);
      s += __shfl_xor(s, 4);
      s += __shfl_xor(s, 8);
      if (c == 0) atomicAdd(&S[grow], s);
    }
  }
  if (!isdiag) {
    // column sums -> S[col] (transpose contribution of this tile)
#pragma unroll
    for (int fn = 0; fn < 4; ++fn) {
      cs[fn] += __shfl_xor(cs[fn], 16);
      cs[fn] += __shfl_xor(cs[fn], 32);
    }
    if (quad == 0) {
#pragma unroll
      for (int fn = 0; fn < 4; ++fn)
        atomicAdd(&S[cb * 128 + wn * 64 + fn * 16 + c], cs[fn]);
    }
  }
}

// loss = mean(log(S_i) - pos_i)
__global__ __launch_bounds__(1024) void finalize_kernel(
    const float* __restrict__ S, const float* __restrict__ pos,
    float* __restrict__ out) {
  const int tid = threadIdx.x;
  float a = 0.f;
  for (int i = tid; i < N_TOT; i += 1024) a += __logf(S[i]) - pos[i];
#pragma unroll
  for (int m = 1; m <= 32; m <<= 1) a += __shfl_xor(a, m);
  __shared__ float red[16];
  if ((tid & 63) == 0) red[tid >> 6] = a;
  __syncthreads();
  if (tid < 16) {
    float v = red[tid];
    v += __shfl_xor(v, 1);
    v += __shfl_xor(v, 2);
    v += __shfl_xor(v, 4);
    v += __shfl_xor(v, 8);
    if (tid == 0) out[0] = v * (1.0f / (float)N_TOT);
  }
}

extern "C" void kernel_launch(void* const* d_in, const int* in_sizes, int n_in,
                              void* d_out, int out_size, void* d_ws,
                              size_t ws_size, hipStream_t stream) {
  const float* z = (const float*)d_in[0];
  float* out = (float*)d_out;
  char* ws = (char*)d_ws;
  float* S = (float*)ws;                                   // N floats
  float* pos = (float*)(ws + N_TOT * sizeof(float));       // N floats
  unsigned short* zn =
      (unsigned short*)(ws + 2 * N_TOT * sizeof(float));   // N*D bf16

  normalize_kernel<<<N_TOT / 4, 256, 0, stream>>>(z, zn, S);
  dim3 grid(33, NT_TILES);
  simclr_tile_kernel<<<grid, 256, 0, stream>>>(zn, S, pos);
  finalize_kernel<<<1, 1024, 0, stream>>>(S, pos, out);
}

// Round 6
// 128.513 us; speedup vs baseline: 1.1074x; 1.1074x over previous
//
#include <hip/hip_runtime.h>
#include <hip/hip_bf16.h>

// NT-Xent (SimCLR) fused loss, MI355X gfx950. Round 6: barrier-free
// wave-private staging. One wave (64 thr) per workgroup owns a 64x64 tile,
// stages its own A/B bands via async global_load_lds into private LDS
// (16 KB/block), and never executes __syncthreads. Stalls are per-wave
// vmcnt waits only, hidden by ~10 self-paced waves/CU (LDS-capped).
// Combines R3's async-LDS staging (good) with R5's barrier-freedom (good),
// avoiding R3's all-wave barrier drains and R5's VGPR-exposed VMEM latency.
//
// ws layout: [S: N floats][pos: N floats][zn: N*D bf16]

#define N_TOT 8192
#define BATCH 4096
#define DIM   256
#define BK    64
#define NB    128                    // 8192 / 64 bands

typedef short bf16x8 __attribute__((ext_vector_type(8)));
typedef float f32x4  __attribute__((ext_vector_type(4)));

__device__ __forceinline__ void load_lds16(const void* g, void* l) {
  __builtin_amdgcn_global_load_lds(
      (const __attribute__((address_space(1))) unsigned int*)g,
      (__attribute__((address_space(3))) unsigned int*)l,
      16, 0, 0);
}

__device__ __forceinline__ unsigned short f32_to_bf16(float f) {
  unsigned int u = __float_as_uint(f);
  u += 0x7fff + ((u >> 16) & 1);   // RNE
  return (unsigned short)(u >> 16);
}

// One wave per row: 64 lanes x float4 = 256 elements. Also zeros S.
__global__ __launch_bounds__(256) void normalize_kernel(
    const float* __restrict__ z, unsigned short* __restrict__ zn,
    float* __restrict__ S) {
  const int wave = threadIdx.x >> 6;
  const int lane = threadIdx.x & 63;
  const int row  = blockIdx.x * 4 + wave;
  float4 v = ((const float4*)(z + (size_t)row * DIM))[lane];
  float ss = v.x * v.x + v.y * v.y + v.z * v.z + v.w * v.w;
#pragma unroll
  for (int m = 1; m <= 32; m <<= 1) ss += __shfl_xor(ss, m);
  float inv = 1.0f / sqrtf(ss);
  ushort4 o;
  o.x = f32_to_bf16(v.x * inv);
  o.y = f32_to_bf16(v.y * inv);
  o.z = f32_to_bf16(v.z * inv);
  o.w = f32_to_bf16(v.w * inv);
  ((ushort4*)(zn + (size_t)row * DIM))[lane] = o;
  if (threadIdx.x < 4) S[blockIdx.x * 4 + threadIdx.x] = 0.0f;
}

// Upper-triangle 64x64 tiles of sim = zn*zn^T*10, fused exp + row/col sums.
// Grid (65, 128): j = blockIdx.x in [0,64], rb_raw = blockIdx.y in [0,128).
// cb_raw = (rb_raw + j) % 128; j==64 only for rb_raw < 64 (each unordered
// band pair exactly once). One 64-lane wave per block; 4x4 fragments of
// 16x16x32 bf16 MFMA; NO __syncthreads anywhere.
__global__ __launch_bounds__(64) void simclr_tile_kernel(
    const unsigned short* __restrict__ zn, float* __restrict__ S,
    float* __restrict__ pos) {
  const int j = blockIdx.x, rb_raw = blockIdx.y;
  if (j == 64 && rb_raw >= 64) return;

  const int lane = threadIdx.x;                 // 0..63 (one wave)
  const int c = lane & 15, quad = lane >> 4;    // MFMA lane coords

  int cb_raw = rb_raw + j;
  if (cb_raw >= NB) cb_raw -= NB;
  const int rb = (cb_raw < rb_raw) ? cb_raw : rb_raw;   // band of 64 rows
  const int cb = (cb_raw < rb_raw) ? rb_raw : cb_raw;
  const bool isdiag = (j == 0);

  __shared__ alignas(16) unsigned short As[64 * BK];    // 8 KB
  __shared__ alignas(16) unsigned short Bs[64 * BK];    // 8 KB

  f32x4 acc[4][4];
#pragma unroll
  for (int i = 0; i < 4; ++i)
#pragma unroll
    for (int jj = 0; jj < 4; ++jj) acc[i][jj] = (f32x4){0.f, 0.f, 0.f, 0.f};

  // Staging: per issue the wave writes 8 rows x 64 bf16 (1 KB); lane l ->
  // row +(l>>3), LDS chunk (l&7); fetches global chunk (l&7)^(row&7)
  // (XOR swizzle -> conflict-free ds_read_b128 fragments; measured 0).
  const int srow   = lane >> 3;                 // 0..7
  const int schunk = (lane & 7) ^ srow;
  const size_t a_row0 = (size_t)rb * 64;
  const size_t b_row0 = (size_t)cb * 64;

#pragma unroll
  for (int kb = 0; kb < DIM / BK; ++kb) {
#pragma unroll
    for (int t = 0; t < 8; ++t) {
      const int rloc = t * 8 + srow;            // 0..63
      load_lds16(zn + (a_row0 + rloc) * DIM + kb * BK + schunk * 8,
                 As + rloc * BK + (lane & 7) * 8);
      load_lds16(zn + (b_row0 + rloc) * DIM + kb * BK + schunk * 8,
                 Bs + rloc * BK + (lane & 7) * 8);
    }
    // No barrier: compiler inserts this wave's own vmcnt wait before the
    // dependent ds_reads; other waves on the CU keep running.
#pragma unroll
    for (int kk = 0; kk < BK / 32; ++kk) {
      const int kc = kk * 4 + quad;
      const int sl = (kc ^ (c & 7)) * 8;        // de-swizzled elem offset
      bf16x8 af[4], bfr[4];
#pragma unroll
      for (int f = 0; f < 4; ++f) {
        af[f]  = *(const bf16x8*)(As + (f * 16 + c) * BK + sl);
        bfr[f] = *(const bf16x8*)(Bs + (f * 16 + c) * BK + sl);
      }
#pragma unroll
      for (int fm = 0; fm < 4; ++fm)
#pragma unroll
        for (int fn = 0; fn < 4; ++fn)
          acc[fm][fn] = __builtin_amdgcn_mfma_f32_16x16x32_bf16(
              af[fm], bfr[fn], acc[fm][fn], 0, 0, 0);
    }
  }

  // Epilogue. C/D layout: row = quad*4 + reg, col = lane&15 per 16x16 frag.
  float cs[4] = {0.f, 0.f, 0.f, 0.f};           // per-lane column partials
#pragma unroll
  for (int fm = 0; fm < 4; ++fm) {
#pragma unroll
    for (int r = 0; r < 4; ++r) {
      const int grow = rb * 64 + fm * 16 + quad * 4 + r;
      float s = 0.f;
#pragma unroll
      for (int fn = 0; fn < 4; ++fn) {
        const int gcol = cb * 64 + fn * 16 + c;
        const float logit = acc[fm][fn][r] * 10.0f;
        float e = __expf(logit);
        if (isdiag && gcol == grow) e = 0.f;    // exclude self-similarity
        if (!isdiag && gcol == grow + BATCH) {  // partner pair (i, i+B):
          pos[grow] = logit;                    // unique writer per element
          pos[gcol] = logit;                    // sim symmetric -> same value
        }
        s += e;
        cs[fn] += e;
      }
      s += __shfl_xor(s, 1);
      s += __shfl_xor(s, 2);
      s += __shfl_xor(s, 4);
      s += __shfl_xor(s, 8);
      if (c == 0) atomicAdd(&S[grow], s);
    }
  }
  if (!isdiag) {
    // column sums -> S[col] (transpose contribution of this tile)
#pragma unroll
    for (int fn = 0; fn < 4; ++fn) {
      cs[fn] += __shfl_xor(cs[fn], 16);
      cs[fn] += __shfl_xor(cs[fn], 32);
    }
    if (quad == 0) {
#pragma unroll
      for (int fn = 0; fn < 4; ++fn)
        atomicAdd(&S[cb * 64 + fn * 16 + c], cs[fn]);
    }
  }
}

// loss = mean(log(S_i) - pos_i)
__global__ __launch_bounds__(1024) void finalize_kernel(
    const float* __restrict__ S, const float* __restrict__ pos,
    float* __restrict__ out) {
  const int tid = threadIdx.x;
  float a = 0.f;
  for (int i = tid; i < N_TOT; i += 1024) a += __logf(S[i]) - pos[i];
#pragma unroll
  for (int m = 1; m <= 32; m <<= 1) a += __shfl_xor(a, m);
  __shared__ float red[16];
  if ((tid & 63) == 0) red[tid >> 6] = a;
  __syncthreads();
  if (tid < 16) {
    float v = red[tid];
    v += __shfl_xor(v, 1);
    v += __shfl_xor(v, 2);
    v += __shfl_xor(v, 4);
    v += __shfl_xor(v, 8);
    if (tid == 0) out[0] = v * (1.0f / (float)N_TOT);
  }
}

extern "C" void kernel_launch(void* const* d_in, const int* in_sizes, int n_in,
                              void* d_out, int out_size, void* d_ws,
                              size_t ws_size, hipStream_t stream) {
  const float* z = (const float*)d_in[0];
  float* out = (float*)d_out;
  char* ws = (char*)d_ws;
  float* S = (float*)ws;                                   // N floats
  float* pos = (float*)(ws + N_TOT * sizeof(float));       // N floats
  unsigned short* zn =
      (unsigned short*)(ws + 2 * N_TOT * sizeof(float));   // N*D bf16

  normalize_kernel<<<N_TOT / 4, 256, 0, stream>>>(z, zn, S);
  dim3 grid(65, NB);
  simclr_tile_kernel<<<grid, 64, 0, stream>>>(zn, S, pos);
  finalize_kernel<<<1, 1024, 0, stream>>>(S, pos, out);
}

// Round 7
// 90.515 us; speedup vs baseline: 1.5723x; 1.4198x over previous
//
#include <hip/hip_runtime.h>
#include <hip/hip_bf16.h>

// NT-Xent (SimCLR) fused loss, MI355X gfx950. Round 7: MX-scaled FP8.
// R3 structure (128x128 tile, 4 waves, shared async-LDS staging, upper-tri
// enumeration, plain atomics + separate finalize) but with fp8 e4m3 data and
// mfma_scale_f32_16x16x128_f8f6f4 (scales = 1.0): halves staged bytes
// (266->133 MB), halves MFMA cycles, halves barrier count (2 kb iters).
//
// ws layout: [S: N floats][pos: N floats][zn8: N*D fp8 bytes]

#define N_TOT 8192
#define BATCH 4096
#define DIM   256
#define BKB   128                    // K-slice bytes per kb iter (fp8)
#define NT_TILES 64                  // 8192 / 128

typedef int   v8i32 __attribute__((ext_vector_type(8)));
typedef float f32x4 __attribute__((ext_vector_type(4)));

__device__ __forceinline__ void load_lds16(const void* g, void* l) {
  __builtin_amdgcn_global_load_lds(
      (const __attribute__((address_space(1))) unsigned int*)g,
      (__attribute__((address_space(3))) unsigned int*)l,
      16, 0, 0);
}

// One wave per row: 64 lanes x float4 -> 4 fp8 bytes/lane. Also zeros S.
__global__ __launch_bounds__(256) void normalize_kernel(
    const float* __restrict__ z, unsigned char* __restrict__ zn8,
    float* __restrict__ S) {
  const int wave = threadIdx.x >> 6;
  const int lane = threadIdx.x & 63;
  const int row  = blockIdx.x * 4 + wave;
  float4 v = ((const float4*)(z + (size_t)row * DIM))[lane];
  float ss = v.x * v.x + v.y * v.y + v.z * v.z + v.w * v.w;
#pragma unroll
  for (int m = 1; m <= 32; m <<= 1) ss += __shfl_xor(ss, m);
  float inv = 1.0f / sqrtf(ss);
  // HW fp8 pack (OCP e4m3 on gfx950): two floats -> low 16 bits.
  int p01 = __builtin_amdgcn_cvt_pk_fp8_f32(v.x * inv, v.y * inv, 0, false);
  int p23 = __builtin_amdgcn_cvt_pk_fp8_f32(v.z * inv, v.w * inv, 0, false);
  unsigned int packed =
      ((unsigned int)p01 & 0xffffu) | ((unsigned int)p23 << 16);
  ((unsigned int*)(zn8 + (size_t)row * DIM))[lane] = packed;
  if (threadIdx.x < 4) S[blockIdx.x * 4 + threadIdx.x] = 0.0f;
}

// Upper-triangle 128x128 tiles of sim = zn*zn^T*10 in fp8 MX MFMA (K=128,
// scale=1.0), fused exp + row/col sums. Grid (33, 64) wrapped enumeration.
__global__ __launch_bounds__(256, 2) void simclr_tile_kernel(
    const unsigned char* __restrict__ zn8, float* __restrict__ S,
    float* __restrict__ pos) {
  const int j = blockIdx.x, rb_raw = blockIdx.y;
  if (j == 32 && rb_raw >= 32) return;

  const int tid = threadIdx.x;
  const int wave = tid >> 6, lane = tid & 63;
  const int wm = wave >> 1, wn = wave & 1;      // wave quadrant (2x2)
  const int c = lane & 15, quad = lane >> 4;    // MFMA lane coords

  int cb_raw = rb_raw + j;
  if (cb_raw >= NT_TILES) cb_raw -= NT_TILES;
  const int rb = (cb_raw < rb_raw) ? cb_raw : rb_raw;
  const int cb = (cb_raw < rb_raw) ? rb_raw : cb_raw;
  const bool isdiag = (j == 0);

  // 128 rows x 128 B per kb-slice, 16 KB per matrix.
  __shared__ alignas(16) unsigned char As[128 * BKB];
  __shared__ alignas(16) unsigned char Bs[128 * BKB];

  f32x4 acc[4][4];
#pragma unroll
  for (int i = 0; i < 4; ++i)
#pragma unroll
    for (int jj = 0; jj < 4; ++jj) acc[i][jj] = (f32x4){0.f, 0.f, 0.f, 0.f};

  // Staging: per issue a wave writes 8 rows x 128 B (1 KB); lane l -> row
  // +(l>>3), LDS 16B-chunk (l&7); fetches global chunk (l&7)^(row&7)
  // (XOR swizzle -> fragment ds_read_b128 is 2-way max = free).
  const int srow   = lane >> 3;
  const int schunk = (lane & 7) ^ srow;
  const size_t a_row0 = (size_t)rb * 128;
  const size_t b_row0 = (size_t)cb * 128;

#pragma unroll
  for (int kb = 0; kb < DIM / BKB; ++kb) {      // 2 iterations
#pragma unroll
    for (int t = 0; t < 4; ++t) {
      const int rloc = wave * 32 + t * 8 + srow;
      load_lds16(zn8 + (a_row0 + rloc) * DIM + kb * BKB + schunk * 16,
                 As + rloc * BKB + (lane & 7) * 16);
      load_lds16(zn8 + (b_row0 + rloc) * DIM + kb * BKB + schunk * 16,
                 Bs + rloc * BKB + (lane & 7) * 16);
    }
    __syncthreads();

    // Fragments: lane (c,quad) holds 32 contiguous k-bytes at k0=quad*32 =
    // swizzled 16B chunks (2q)^(c&7) and ((2q)^(c&7))^1 of its row.
    const int c0 = (2 * quad) ^ (c & 7);
    v8i32 af[4], bfr[4];
#pragma unroll
    for (int f = 0; f < 4; ++f) {
      const int4* Ar = (const int4*)(As + (size_t)(wm * 64 + f * 16 + c) * BKB);
      const int4* Br = (const int4*)(Bs + (size_t)(wn * 64 + f * 16 + c) * BKB);
      int4 alo = Ar[c0], ahi = Ar[c0 ^ 1];
      int4 blo = Br[c0], bhi = Br[c0 ^ 1];
      af[f]  = (v8i32){alo.x, alo.y, alo.z, alo.w, ahi.x, ahi.y, ahi.z, ahi.w};
      bfr[f] = (v8i32){blo.x, blo.y, blo.z, blo.w, bhi.x, bhi.y, bhi.z, bhi.w};
    }
#pragma unroll
    for (int fm = 0; fm < 4; ++fm)
#pragma unroll
      for (int fn = 0; fn < 4; ++fn)
        acc[fm][fn] = __builtin_amdgcn_mfma_scale_f32_16x16x128_f8f6f4(
            af[fm], bfr[fn], acc[fm][fn],
            0, 0,                 // cbsz = fp8(A), blgp = fp8(B)
            0, 0x7f,              // opsel_a, scale_a = E8M0 1.0
            0, 0x7f);             // opsel_b, scale_b = E8M0 1.0
    __syncthreads();
  }

  // Epilogue. C/D layout: row = quad*4 + reg, col = lane&15 per 16x16 frag.
  float cs[4] = {0.f, 0.f, 0.f, 0.f};           // per-lane column partials
#pragma unroll
  for (int fm = 0; fm < 4; ++fm) {
#pragma unroll
    for (int r = 0; r < 4; ++r) {
      const int grow = rb * 128 + wm * 64 + fm * 16 + quad * 4 + r;
      float s = 0.f;
#pragma unroll
      for (int fn = 0; fn < 4; ++fn) {
        const int gcol = cb * 128 + wn * 64 + fn * 16 + c;
        const float logit = acc[fm][fn][r] * 10.0f;
        float e = __expf(logit);
        if (isdiag && gcol == grow) e = 0.f;    // exclude self-similarity
        if (!isdiag && gcol == grow + BATCH) {  // partner pair (i, i+B):
          pos[grow] = logit;                    // unique writer per element
          pos[gcol] = logit;                    // sim symmetric -> same value
        }
        s += e;
        cs[fn] += e;
      }
      s += __shfl_xor(s, 1);
      s += __shfl_xor(s, 2);
      s += __shfl_xor(s, 4);
      s += __shfl_xor(s, 8);
      if (c == 0) atomicAdd(&S[grow], s);
    }
  }
  if (!isdiag) {
    // column sums -> S[col] (transpose contribution of this tile)
#pragma unroll
    for (int fn = 0; fn < 4; ++fn) {
      cs[fn] += __shfl_xor(cs[fn], 16);
      cs[fn] += __shfl_xor(cs[fn], 32);
    }
    if (quad == 0) {
#pragma unroll
      for (int fn = 0; fn < 4; ++fn)
        atomicAdd(&S[cb * 128 + wn * 64 + fn * 16 + c], cs[fn]);
    }
  }
}

// loss = mean(log(S_i) - pos_i)
__global__ __launch_bounds__(1024) void finalize_kernel(
    const float* __restrict__ S, const float* __restrict__ pos,
    float* __restrict__ out) {
  const int tid = threadIdx.x;
  float a = 0.f;
  for (int i = tid; i < N_TOT; i += 1024) a += __logf(S[i]) - pos[i];
#pragma unroll
  for (int m = 1; m <= 32; m <<= 1) a += __shfl_xor(a, m);
  __shared__ float red[16];
  if ((tid & 63) == 0) red[tid >> 6] = a;
  __syncthreads();
  if (tid < 16) {
    float v = red[tid];
    v += __shfl_xor(v, 1);
    v += __shfl_xor(v, 2);
    v += __shfl_xor(v, 4);
    v += __shfl_xor(v, 8);
    if (tid == 0) out[0] = v * (1.0f / (float)N_TOT);
  }
}

extern "C" void kernel_launch(void* const* d_in, const int* in_sizes, int n_in,
                              void* d_out, int out_size, void* d_ws,
                              size_t ws_size, hipStream_t stream) {
  const float* z = (const float*)d_in[0];
  float* out = (float*)d_out;
  char* ws = (char*)d_ws;
  float* S = (float*)ws;                                   // N floats
  float* pos = (float*)(ws + N_TOT * sizeof(float));       // N floats
  unsigned char* zn8 =
      (unsigned char*)(ws + 2 * N_TOT * sizeof(float));    // N*D fp8

  normalize_kernel<<<N_TOT / 4, 256, 0, stream>>>(z, zn8, S);
  dim3 grid(33, NT_TILES);
  simclr_tile_kernel<<<grid, 256, 0, stream>>>(zn8, S, pos);
  finalize_kernel<<<1, 1024, 0, stream>>>(S, pos, out);
}

// Round 8
// 90.265 us; speedup vs baseline: 1.5766x; 1.0028x over previous
//
#include <hip/hip_runtime.h>
#include <hip/hip_bf16.h>

// NT-Xent (SimCLR) fused loss, MI355X gfx950. Round 8: persistent row-band
// blocks. Grid 8x64 = 512 blocks (exactly 2/CU, one dispatch round); each
// block owns row band rb (A staged ONCE, A-fragments register-resident) and
// processes 4-5 tiles j = 4g..4g+3 (+ j=32 partner tile for g==0, rb<32).
// Per tile only B restages; B(t+1) staging issues right after the
// post-compute barrier and is hidden under tile-t's exp/shuffle/atomic
// epilogue. FP8 e4m3 data + mfma_scale_f32_16x16x128_f8f6f4 (scale=1.0).
//
// ws layout: [S: N floats][pos: N floats][zn8: N*D fp8 bytes]

#define N_TOT 8192
#define BATCH 4096
#define DIM   256                    // fp8 bytes per row
#define NT_TILES 64                  // 8192 / 128

typedef int   v8i32 __attribute__((ext_vector_type(8)));
typedef float f32x4 __attribute__((ext_vector_type(4)));

__device__ __forceinline__ void load_lds16(const void* g, void* l) {
  __builtin_amdgcn_global_load_lds(
      (const __attribute__((address_space(1))) unsigned int*)g,
      (__attribute__((address_space(3))) unsigned int*)l,
      16, 0, 0);
}

// One wave per row: 64 lanes x float4 -> 4 fp8 bytes/lane. Also zeros S.
__global__ __launch_bounds__(256) void normalize_kernel(
    const float* __restrict__ z, unsigned char* __restrict__ zn8,
    float* __restrict__ S) {
  const int wave = threadIdx.x >> 6;
  const int lane = threadIdx.x & 63;
  const int row  = blockIdx.x * 4 + wave;
  float4 v = ((const float4*)(z + (size_t)row * DIM))[lane];
  float ss = v.x * v.x + v.y * v.y + v.z * v.z + v.w * v.w;
#pragma unroll
  for (int m = 1; m <= 32; m <<= 1) ss += __shfl_xor(ss, m);
  float inv = 1.0f / sqrtf(ss);
  int p01 = __builtin_amdgcn_cvt_pk_fp8_f32(v.x * inv, v.y * inv, 0, false);
  int p23 = __builtin_amdgcn_cvt_pk_fp8_f32(v.z * inv, v.w * inv, 0, false);
  unsigned int packed =
      ((unsigned int)p01 & 0xffffu) | ((unsigned int)p23 << 16);
  ((unsigned int*)(zn8 + (size_t)row * DIM))[lane] = packed;
  if (threadIdx.x < 4) S[blockIdx.x * 4 + threadIdx.x] = 0.0f;
}

// Stage a 128-row band (full K = 256 B/row = 32 KB) into LDS.
// Per issue a wave writes 4 rows x 256 B = 1 KB; lane l -> row +(l>>4),
// LDS 16B-chunk (l&15); fetches global chunk (l&15)^(row&15) (XOR swizzle
// keeps fragment ds_read_b128 bank-balanced; measured 0 conflicts).
__device__ __forceinline__ void stage_band(
    const unsigned char* __restrict__ zn8, unsigned char* lds, int band,
    int wave, int lane) {
  const int srow = lane >> 4;          // 0..3
  const int slds = lane & 15;          // LDS chunk within row
  const size_t r0 = (size_t)band * 128;
#pragma unroll
  for (int t = 0; t < 8; ++t) {
    const int rloc = wave * 32 + t * 4 + srow;          // 0..127
    const int gch  = slds ^ (rloc & 15);                // swizzled source
    load_lds16(zn8 + (r0 + rloc) * DIM + gch * 16,
               lds + rloc * 256 + slds * 16);
  }
}

// Read one (row, k-half) fragment (32 bytes) from a swizzled band.
__device__ __forceinline__ v8i32 read_frag(const unsigned char* lds, int row,
                                           int h, int quad) {
  const int4* R = (const int4*)(lds + (size_t)row * 256);
  const int base = 8 * h + 2 * quad;   // even global chunk of this lane
  const int cc = row & 15;
  int4 lo = R[base ^ cc];
  int4 hi = R[(base + 1) ^ cc];
  return (v8i32){lo.x, lo.y, lo.z, lo.w, hi.x, hi.y, hi.z, hi.w};
}

__global__ __launch_bounds__(256, 2) void simclr_tile_kernel(
    const unsigned char* __restrict__ zn8, float* __restrict__ S,
    float* __restrict__ pos) {
  const int g = blockIdx.x;                    // j-group 0..7
  const int rb = blockIdx.y;                   // row band 0..63 (A, fixed)
  const int tid = threadIdx.x;
  const int wave = tid >> 6, lane = tid & 63;
  const int wm = wave >> 1, wn = wave & 1;     // wave quadrant (2x2)
  const int c = lane & 15, quad = lane >> 4;   // MFMA lane coords

  __shared__ alignas(16) unsigned char As[128 * 256];   // 32 KB
  __shared__ alignas(16) unsigned char Bs[128 * 256];   // 32 KB

  const int ntile = (g == 0 && rb < 32) ? 5 : 4;  // g0 also does j=32

  stage_band(zn8, Bs, (rb + g * 4) & 63, wave, lane);   // B for tile 0
  stage_band(zn8, As, rb, wave, lane);                  // A, once per block
  __syncthreads();

  // A-fragments -> registers, reused across all tiles of this block.
  v8i32 af[4][2];
#pragma unroll
  for (int f = 0; f < 4; ++f)
#pragma unroll
    for (int h = 0; h < 2; ++h)
      af[f][h] = read_frag(As, wm * 64 + f * 16 + c, h, quad);

  for (int t = 0; t < ntile; ++t) {
    const int jj = (t == 4) ? 32 : (g * 4 + t);
    const int cbt = (rb + jj) & 63;
    const bool isdiag = (g == 0 && t == 0);

    f32x4 acc[4][4];
#pragma unroll
    for (int i = 0; i < 4; ++i)
#pragma unroll
      for (int k = 0; k < 4; ++k) acc[i][k] = (f32x4){0.f, 0.f, 0.f, 0.f};

#pragma unroll
    for (int h = 0; h < 2; ++h) {
      v8i32 bfr[4];
#pragma unroll
      for (int f = 0; f < 4; ++f)
        bfr[f] = read_frag(Bs, wn * 64 + f * 16 + c, h, quad);
#pragma unroll
      for (int fm = 0; fm < 4; ++fm)
#pragma unroll
        for (int fn = 0; fn < 4; ++fn)
          acc[fm][fn] = __builtin_amdgcn_mfma_scale_f32_16x16x128_f8f6f4(
              af[fm][h], bfr[fn], acc[fm][fn],
              0, 0,                 // cbsz = fp8(A), blgp = fp8(B)
              0, 0x7f,              // opsel_a, scale_a = E8M0 1.0
              0, 0x7f);             // opsel_b, scale_b = E8M0 1.0
    }
    __syncthreads();                // all waves done reading Bs for tile t

    // Prefetch next B band NOW; its latency hides under the epilogue below.
    if (t + 1 < ntile) {
      const int jn = (t + 1 == 4) ? 32 : (g * 4 + t + 1);
      stage_band(zn8, Bs, (rb + jn) & 63, wave, lane);
    }

    // Epilogue. C/D layout: row = quad*4 + reg, col = lane&15 per frag.
    float cs[4] = {0.f, 0.f, 0.f, 0.f};       // per-lane column partials
#pragma unroll
    for (int fm = 0; fm < 4; ++fm) {
#pragma unroll
      for (int r = 0; r < 4; ++r) {
        const int grow = rb * 128 + wm * 64 + fm * 16 + quad * 4 + r;
        float s = 0.f;
#pragma unroll
        for (int fn = 0; fn < 4; ++fn) {
          const int gcol = cbt * 128 + wn * 64 + fn * 16 + c;
          const float logit = acc[fm][fn][r] * 10.0f;
          float e = __expf(logit);
          if (isdiag && gcol == grow) e = 0.f;     // exclude self-similarity
          if ((gcol ^ grow) == BATCH) {            // partner pair i <-> i^B
            pos[grow] = logit;                     // unique writer/elem
            pos[gcol] = logit;                     // sim symmetric
          }
          s += e;
          cs[fn] += e;
        }
        s += __shfl_xor(s, 1);
        s += __shfl_xor(s, 2);
        s += __shfl_xor(s, 4);
        s += __shfl_xor(s, 8);
        if (c == 0) atomicAdd(&S[grow], s);
      }
    }
    if (!isdiag) {
      // column sums -> S[col] (transpose contribution of this tile)
#pragma unroll
      for (int fn = 0; fn < 4; ++fn) {
        cs[fn] += __shfl_xor(cs[fn], 16);
        cs[fn] += __shfl_xor(cs[fn], 32);
      }
      if (quad == 0) {
#pragma unroll
        for (int fn = 0; fn < 4; ++fn)
          atomicAdd(&S[cbt * 128 + wn * 64 + fn * 16 + c], cs[fn]);
      }
    }

    if (t + 1 < ntile) __syncthreads();  // staging drained before next reads
  }
}

// loss = mean(log(S_i) - pos_i)
__global__ __launch_bounds__(1024) void finalize_kernel(
    const float* __restrict__ S, const float* __restrict__ pos,
    float* __restrict__ out) {
  const int tid = threadIdx.x;
  float a = 0.f;
  for (int i = tid; i < N_TOT; i += 1024) a += __logf(S[i]) - pos[i];
#pragma unroll
  for (int m = 1; m <= 32; m <<= 1) a += __shfl_xor(a, m);
  __shared__ float red[16];
  if ((tid & 63) == 0) red[tid >> 6] = a;
  __syncthreads();
  if (tid < 16) {
    float v = red[tid];
    v += __shfl_xor(v, 1);
    v += __shfl_xor(v, 2);
    v += __shfl_xor(v, 4);
    v += __shfl_xor(v, 8);
    if (tid == 0) out[0] = v * (1.0f / (float)N_TOT);
  }
}

extern "C" void kernel_launch(void* const* d_in, const int* in_sizes, int n_in,
                              void* d_out, int out_size, void* d_ws,
                              size_t ws_size, hipStream_t stream) {
  const float* z = (const float*)d_in[0];
  float* out = (float*)d_out;
  char* ws = (char*)d_ws;
  float* S = (float*)ws;                                   // N floats
  float* pos = (float*)(ws + N_TOT * sizeof(float));       // N floats
  unsigned char* zn8 =
      (unsigned char*)(ws + 2 * N_TOT * sizeof(float));    // N*D fp8

  normalize_kernel<<<N_TOT / 4, 256, 0, stream>>>(z, zn8, S);
  dim3 grid(8, NT_TILES);
  simclr_tile_kernel<<<grid, 256, 0, stream>>>(zn8, S, pos);
  finalize_kernel<<<1, 1024, 0, stream>>>(S, pos, out);
}